// Round 2
// baseline (35196.649 us; speedup 1.0000x reference)
//
#include <hip/hip_runtime.h>

// B=128, S=1024, F_IN=128, H=256, BB=256, F_OUT=128
#define Bn   128
#define Sn   1024
#define FIN  128
#define Hn   256
#define FOUT 128
#define TW   8     // workgroups per team
#define TEAMS 32   // 32 teams x 8 WGs = 256 WGs = 1 per CU
#define Mb   4     // batch elements per team

// workspace layout (bytes):
//   [0, 786432)        packed fp16 weights, per-WG-sliced (see pack_w)
//   [786432, 917504)   team activation buffers: per team 4096 B = z[4][256] f16 | h[4][256] f16
//   [917504, 921600)   team barrier counters, 128 B apart
#define W4_OFF   98304     // halves
#define WO_OFF   360448    // halves
#define WS_HALVES 393216
#define TEAMBUF_BYTE 786432
#define CNT_BYTE     917504
#define SMEM_BYTES   122368

typedef _Float16 h2 __attribute__((ext_vector_type(2)));
typedef _Float16 h8 __attribute__((ext_vector_type(8)));

__device__ __forceinline__ float dot2f(h2 a, h2 b, float c) {
#if __has_builtin(__builtin_amdgcn_fdot2)
  return __builtin_amdgcn_fdot2(a, b, c, false);   // v_dot2_f32_f16
#else
  return c + (float)a[0] * (float)b[0] + (float)a[1] * (float)b[1];
#endif
}
__device__ __forceinline__ float dot8f(h8 v, h8 w, float c) {
  h2 v0 = {v[0], v[1]}, v1 = {v[2], v[3]}, v2 = {v[4], v[5]}, v3 = {v[6], v[7]};
  h2 w0 = {w[0], w[1]}, w1 = {w[2], w[3]}, w2 = {w[4], w[5]}, w3 = {w[6], w[7]};
  c = dot2f(v0, w0, c); c = dot2f(v1, w1, c);
  c = dot2f(v2, w2, c); c = dot2f(v3, w3, c);
  return c;
}
__device__ __forceinline__ void dot8_4(h8 v, h8 w, float& c0, float& c1, float& c2, float& c3) {
  h2 v0 = {v[0], v[1]}, v1 = {v[2], v[3]}, v2 = {v[4], v[5]}, v3 = {v[6], v[7]};
  h2 w0 = {w[0], w[1]}, w1 = {w[2], w[3]}, w2 = {w[4], w[5]}, w3 = {w[6], w[7]};
  c0 = dot2f(v0, w0, c0); c1 = dot2f(v1, w1, c1);
  c2 = dot2f(v2, w2, c2); c3 = dot2f(v3, w3, c3);
}

// ---- pack weights fp32->fp16 into per-WG LDS-image slices ----
// Wb:  [w8][k8:48][jl:32][r:8]   (j = 32w+jl, k = 8*k8+r)
// W4:  [w8][k8:32][head:4][jl:32][r:8]
// Wo:  [w8][k8:32][j16:16][r:8]  (j = 16w+j16)
// block 1536 zeroes the team barrier counters.
__global__ __launch_bounds__(256) void pack_w(
    const float* __restrict__ Wb, const float* __restrict__ W1,
    const float* __restrict__ W2, const float* __restrict__ W3,
    const float* __restrict__ W4, const float* __restrict__ Wo,
    _Float16* __restrict__ ws) {
  if (blockIdx.x == 1536) {
    int* c = (int*)((char*)ws + CNT_BYTE);
    for (int i = threadIdx.x; i < 1024; i += 256) c[i] = 0;
    return;
  }
  int p = blockIdx.x * 256 + threadIdx.x;
  float v;
  if (p < W4_OFF) {                       // backbone slice image
    int r = p & 7, jl = (p >> 3) & 31;
    int t1 = p >> 8;                      // = w*48 + k8
    int w = t1 / 48, k8 = t1 - w * 48;
    v = Wb[(k8 * 8 + r) * 256 + (w * 32 + jl)];
  } else if (p < WO_OFF) {                // fused heads image
    int q = p - W4_OFF;
    int r = q & 7, jl = (q >> 3) & 31, hd = (q >> 8) & 3;
    int t2 = q >> 10;                     // = w*32 + k8
    int k8 = t2 & 31, w = t2 >> 5;
    const float* Ws = (hd == 0) ? W1 : (hd == 1) ? W2 : (hd == 2) ? W3 : W4;
    v = Ws[(k8 * 8 + r) * 256 + (w * 32 + jl)];
  } else {                                // Wout image
    int q = p - WO_OFF;
    int r = q & 7, j16 = (q >> 3) & 15;
    int t3 = q >> 7;                      // = w*32 + k8
    int k8 = t3 & 31, w = t3 >> 5;
    v = Wo[(k8 * 8 + r) * 128 + (w * 16 + j16)];
  }
  ws[p] = (_Float16)v;
}

__device__ __forceinline__ void team_barrier(int* cnt, int target) {
  __threadfence();          // drain this thread's global stores (agent scope)
  __syncthreads();          // all WG threads' stores drained before arrival
  if (threadIdx.x == 0) {
    __hip_atomic_fetch_add(cnt, 1, __ATOMIC_RELAXED, __HIP_MEMORY_SCOPE_AGENT);
    while (__hip_atomic_load(cnt, __ATOMIC_RELAXED, __HIP_MEMORY_SCOPE_AGENT) < target)
      __builtin_amdgcn_s_sleep(1);
    __builtin_amdgcn_fence(__ATOMIC_ACQUIRE, "agent");   // invalidate L1/L2 stale lines
  }
  __syncthreads();
}

__device__ __forceinline__ void store_f16_agent(_Float16* p, float v) {
  unsigned short u = __builtin_bit_cast(unsigned short, (_Float16)v);
  __hip_atomic_store((unsigned short*)p, u, __ATOMIC_RELAXED, __HIP_MEMORY_SCOPE_AGENT);
}

// Team kernel: team = blockIdx%32, member w = blockIdx/32 (stride-32 members
// share blockIdx%8 -> same XCD under round-robin dispatch; heuristic only).
// Each WG holds N-slices of all weights in LDS; M=4 batches advance together.
extern "C" __global__ __launch_bounds__(256, 1)
void cfc_team(const float* __restrict__ x, const float* __restrict__ ts,
              const float* __restrict__ bb, const float* __restrict__ bf1,
              const float* __restrict__ bf2, const float* __restrict__ bta,
              const float* __restrict__ btb, const float* __restrict__ bo,
              _Float16* __restrict__ ws, float* __restrict__ out) {
  extern __shared__ char smem[];
  _Float16* sWb = (_Float16*)smem;                 // 12288 h, 24576 B
  _Float16* sW4 = (_Float16*)(smem + 24576);       // 32768 h, 65536 B
  _Float16* sWo = (_Float16*)(smem + 90112);       // 4096 h,  8192 B
  _Float16* xh  = (_Float16*)(smem + 98304);       // [4][384] f16 (x | h)
  _Float16* zf  = (_Float16*)(smem + 101376);      // [4][256] f16
  float*    tsb = (float*)(smem + 103424);         // [4][1024] f32
  float*    scrZ = (float*)(smem + 119808);        // 128 f
  float*    scrH = (float*)(smem + 120320);        // 256 f
  float*    scrY = (float*)(smem + 121344);        // 192 f

  const int tid = threadIdx.x;
  const int team = blockIdx.x & 31;
  const int w    = blockIdx.x >> 5;

  _Float16* team_z = ws + TEAMBUF_BYTE / 2 + team * 2048;
  _Float16* team_h = team_z + 1024;
  int* cnt = (int*)((char*)ws + CNT_BYTE + team * 128);

  // ---- stage weights global->LDS (one-time) ----
  { const uint4* g = (const uint4*)(ws + (size_t)w * 12288);
    uint4* l = (uint4*)sWb;
    for (int i = tid; i < 1536; i += 256) l[i] = g[i];
    g = (const uint4*)(ws + W4_OFF + (size_t)w * 32768);
    l = (uint4*)sW4;
    for (int i = tid; i < 4096; i += 256) l[i] = g[i];
    g = (const uint4*)(ws + WO_OFF + (size_t)w * 4096);
    l = (uint4*)sWo;
    for (int i = tid; i < 512; i += 256) l[i] = g[i]; }
  // ---- stage ts rows (batches are contiguous) ----
  { const float* g = ts + (size_t)team * (Mb * Sn);
    for (int i = tid; i < Mb * Sn; i += 256) tsb[i] = g[i]; }
  // ---- h(0)=0, x(0) into xh ----
  { int m = tid >> 6, o = (tid & 63) * 4;
    uint2 zz; zz.x = 0; zz.y = 0;
    *(uint2*)&xh[m * 384 + 128 + o] = zz; }
  { int m = tid >> 6, c = (tid & 63) * 2;
    float2 xv = *(const float2*)(x + ((size_t)(team * Mb + m) * Sn) * FIN + c);
    h2 hx; hx[0] = (_Float16)xv.x; hx[1] = (_Float16)xv.y;
    *(h2*)&xh[m * 384 + c] = hx; }

  // ---- per-role bias preloads ----
  const int mZ = tid & 3, jlZ = (tid >> 2) & 31, khZ = tid >> 7;
  float bbj = 0.f;
  if (!khZ) bbj = bb[w * 32 + jlZ];
  const int qH = tid >> 2, mH = tid & 3, hpH = qH >> 5, jlH = qH & 31;
  const int jH = w * 32 + jlH;
  const float bA = hpH ? bta[jH] : bf1[jH];
  const float bB = hpH ? btb[jH] : bf2[jH];
  const int mY = tid & 3, j16 = (tid >> 2) & 15, kq = tid >> 6;
  float boj = 0.f;
  if (!kq) boj = bo[w * 16 + j16];
  const int mX = tid >> 6, cX = (tid & 63) * 2;
  __syncthreads();

  int bar = 0;
  for (int st = 0; st < Sn; ++st) {
    // ---- Z: z = tanh([x,h] @ Wb + bb), K=384 split 2 ways ----
    float a0 = 0.f, a1 = 0.f, a2 = 0.f, a3 = 0.f;
#pragma unroll 4
    for (int k8 = khZ * 24; k8 < khZ * 24 + 24; ++k8) {
      h8 v = *(const h8*)&xh[mZ * 384 + k8 * 8];
      h8 wt = *(const h8*)&sWb[(k8 * 32 + jlZ) * 8];
      dot8_4(v, wt, a0, a1, a2, a3);
    }
    float zs = a0 + a1 + a2 + a3;
    if (khZ) scrZ[tid - 128] = zs;
    __syncthreads();
    if (!khZ) {
      float tot = zs + scrZ[tid] + bbj;
      store_f16_agent(&team_z[mZ * 256 + w * 32 + jlZ], tanhf(tot));
    }
    bar++; team_barrier(cnt, bar * TW);                 // z published

    { uint2 r = ((const uint2*)team_z)[tid];            // 2 KB coop load
      ((uint2*)zf)[tid] = r; }
    float2 xv; xv.x = 0.f; xv.y = 0.f;                  // prefetch x(st+1)
    if (st + 1 < Sn)
      xv = *(const float2*)(x + ((size_t)(team * Mb + mX) * Sn + st + 1) * FIN + cX);
    __syncthreads();                                    // zf ready

    // ---- H: [ff1|ff2] or [ta|tb] slices, K=256, 4 accum chains ----
    float g1a = 0.f, g1b = 0.f, g2a = 0.f, g2b = 0.f;
#pragma unroll 4
    for (int k8 = 0; k8 < 32; k8 += 2) {
      h8 v0 = *(const h8*)&zf[mH * 256 + k8 * 8];
      int base0 = ((k8 * 4 + 2 * hpH) * 32 + jlH) * 8;
      h8 w10 = *(const h8*)&sW4[base0];
      h8 w20 = *(const h8*)&sW4[base0 + 256];
      g1a = dot8f(v0, w10, g1a);
      g2a = dot8f(v0, w20, g2a);
      h8 v1 = *(const h8*)&zf[mH * 256 + k8 * 8 + 8];
      int base1 = (((k8 + 1) * 4 + 2 * hpH) * 32 + jlH) * 8;
      h8 w11 = *(const h8*)&sW4[base1];
      h8 w21 = *(const h8*)&sW4[base1 + 256];
      g1b = dot8f(v1, w11, g1b);
      g2b = dot8f(v1, w21, g2b);
    }
    float g1 = g1a + g1b + bA, g2 = g2a + g2b + bB;
    if (hpH) { scrH[(mH * 32 + jlH) * 2] = g1; scrH[(mH * 32 + jlH) * 2 + 1] = g2; }
    __syncthreads();
    if (!hpH) {
      float ga = scrH[(mH * 32 + jlH) * 2], gb = scrH[(mH * 32 + jlH) * 2 + 1];
      float tt = tsb[mH * 1024 + st];
      float sg = 1.f / (1.f + __expf(-(ga * tt + gb)));
      float hn = tanhf(g1) * (1.f - sg) + sg * tanhf(g2);
      store_f16_agent(&team_h[mH * 256 + w * 32 + jlH], hn);
    }
    bar++; team_barrier(cnt, bar * TW);                 // h published

    { int m = tid >> 6, o = (tid & 63) * 4;             // 2 KB coop load of h
      *(uint2*)&xh[m * 384 + 128 + o] = *(const uint2*)&team_h[m * 256 + o]; }
    __syncthreads();                                    // h ready

    // ---- Y: y = h @ Wout + bo, K=256 split 4 ways ----
    float y0 = 0.f, y1 = 0.f, y2 = 0.f, y3 = 0.f;
#pragma unroll
    for (int k8 = kq * 8; k8 < kq * 8 + 8; ++k8) {
      h8 v = *(const h8*)&xh[mY * 384 + 128 + k8 * 8];
      h8 wt = *(const h8*)&sWo[(k8 * 16 + j16) * 8];
      dot8_4(v, wt, y0, y1, y2, y3);
    }
    float ysm = y0 + y1 + y2 + y3;
    if (kq) scrY[(kq - 1) * 64 + mY * 16 + j16] = ysm;
    __syncthreads();
    if (!kq) {
      float y = ysm + scrY[mY * 16 + j16] + scrY[64 + mY * 16 + j16] +
                scrY[128 + mY * 16 + j16] + boj;
      out[((size_t)(team * Mb + mY) * Sn + st) * FOUT + w * 16 + j16] = y;
    }
    if (st + 1 < Sn) {                                  // commit x prefetch
      h2 hx; hx[0] = (_Float16)xv.x; hx[1] = (_Float16)xv.y;
      *(h2*)&xh[mX * 384 + cX] = hx;
    }
    __syncthreads();                                    // x ready for next Z
  }
}

extern "C" void kernel_launch(void* const* d_in, const int* in_sizes, int n_in,
                              void* d_out, int out_size, void* d_ws, size_t ws_size,
                              hipStream_t stream) {
  const float* x   = (const float*)d_in[0];
  const float* ts  = (const float*)d_in[1];
  const float* Wb  = (const float*)d_in[2];
  const float* bb  = (const float*)d_in[3];
  const float* W1  = (const float*)d_in[4];
  const float* bf1 = (const float*)d_in[5];
  const float* W2  = (const float*)d_in[6];
  const float* bf2 = (const float*)d_in[7];
  const float* W3  = (const float*)d_in[8];
  const float* bta = (const float*)d_in[9];
  const float* W4  = (const float*)d_in[10];
  const float* btb = (const float*)d_in[11];
  const float* Wo  = (const float*)d_in[12];
  const float* bo  = (const float*)d_in[13];
  float* out = (float*)d_out;
  _Float16* ws = (_Float16*)d_ws;

  pack_w<<<1537, 256, 0, stream>>>(Wb, W1, W2, W3, W4, Wo, ws);

  static int attr_set = 0;
  (void)attr_set;
  hipFuncSetAttribute((const void*)cfc_team,
                      hipFuncAttributeMaxDynamicSharedMemorySize, SMEM_BYTES);
  void* args[] = {(void*)&x, (void*)&ts, (void*)&bb, (void*)&bf1, (void*)&bf2,
                  (void*)&bta, (void*)&btb, (void*)&bo, (void*)&ws, (void*)&out};
  hipLaunchCooperativeKernel((const void*)cfc_team, dim3(TEAMS * TW), dim3(256),
                             args, SMEM_BYTES, stream);
}

// Round 3
// 18092.613 us; speedup vs baseline: 1.9454x; 1.9454x over previous
//
#include <hip/hip_runtime.h>

// B=128, S=1024, F_IN=128, H=256, BB=256, F_OUT=128
#define Bn   128
#define Sn   1024
#define FIN  128
#define Hn   256
#define FOUT 128
#define NT   512   // threads per WG (8 waves)

// packed weight layout in d_ws (halves):
//   Wb_p [48][256][8]  -> 98304
//   W4_p [32][1024][8] -> 262144   (N = [ff1|ff2|ta|tb])
//   Wo_p [32][128][8]  -> 32768
#define WB_OFF 0
#define W4_OFF 98304
#define WO_OFF 360448
#define WS_HALVES 393216

// dynamic LDS layout (bytes)
#define OWO 0        // Wo image        65536
#define OWB 65536    // 10 Wb slices    40960
#define OW4 106496   // 2 W4 slices     32768
#define OXH 139264   // xh[384] f16       768
#define OZF 140032   // zf[256] f16       512
#define OTS 140544   // ts[1024] f32     4096
#define OSH 144640   // scrH[512] f32    2048
#define OSY 146688   // scrY[384] f32    1536
#define SMEM2 148224

typedef _Float16 h2 __attribute__((ext_vector_type(2)));
typedef _Float16 h8 __attribute__((ext_vector_type(8)));

__device__ __forceinline__ float dot2f(h2 a, h2 b, float c) {
#if __has_builtin(__builtin_amdgcn_fdot2)
  return __builtin_amdgcn_fdot2(a, b, c, false);   // v_dot2_f32_f16
#else
  return c + (float)a[0] * (float)b[0] + (float)a[1] * (float)b[1];
#endif
}
__device__ __forceinline__ void dot8_4(h8 v, h8 w, float& c0, float& c1, float& c2, float& c3) {
  h2 v0 = {v[0], v[1]}, v1 = {v[2], v[3]}, v2 = {v[4], v[5]}, v3 = {v[6], v[7]};
  h2 w0 = {w[0], w[1]}, w1 = {w[2], w[3]}, w2 = {w[4], w[5]}, w3 = {w[6], w[7]};
  c0 = dot2f(v0, w0, c0); c1 = dot2f(v1, w1, c1);
  c2 = dot2f(v2, w2, c2); c3 = dot2f(v3, w3, c3);
}

// fp32 -> fp16 packing (same layout as round 1; it is verified-correct)
__global__ __launch_bounds__(256) void pack_w(
    const float* __restrict__ Wb, const float* __restrict__ W1,
    const float* __restrict__ W2, const float* __restrict__ W3,
    const float* __restrict__ W4, const float* __restrict__ Wo,
    _Float16* __restrict__ ws) {
  int p = blockIdx.x * 256 + threadIdx.x;
  if (p >= WS_HALVES) return;
  float v;
  if (p < W4_OFF) {                       // backbone [384,256] row-major
    int r = p & 7, j = (p >> 3) & 255;
    int k = ((p >> 11) << 3) | r;
    v = Wb[k * 256 + j];
  } else if (p < WO_OFF) {                // heads concat: N = [ff1|ff2|ta|tb]
    int q = p - W4_OFF;
    int r = q & 7, j = (q >> 3) & 1023;
    int k = ((q >> 13) << 3) | r;
    int jj = j & 255;
    const float* Ws = (j < 256) ? W1 : (j < 512) ? W2 : (j < 768) ? W3 : W4;
    v = Ws[k * 256 + jj];
  } else {                                // Wout [256,128]
    int q = p - WO_OFF;
    int r = q & 7, j = (q >> 3) & 127;
    int k = ((q >> 10) << 3) | r;
    v = Wo[k * 128 + j];
  }
  ws[p] = (_Float16)v;
}

// full K=256 dot against the 4-head matrix column n: chunks 0,1 from LDS,
// chunks 2..31 streamed from L2 with an explicit 8-deep double buffer.
__device__ __forceinline__ float hchain(const _Float16* __restrict__ gW /* chunk2 of col n */,
                                        const _Float16* __restrict__ zlds,
                                        const _Float16* __restrict__ lW /* sW4 + n*8 */) {
  const int CS = 1024 * 8;   // halves per k8 chunk
  h8 A[8], Bb[8];
#pragma unroll
  for (int i = 0; i < 8; i++) A[i] = *(const h8*)(gW + (size_t)i * CS);
  float c0 = 0.f, c1 = 0.f, c2 = 0.f, c3 = 0.f;
  { h8 v0 = *(const h8*)(zlds);     h8 w0 = *(const h8*)(lW);
    dot8_4(v0, w0, c0, c1, c2, c3);
    h8 v1 = *(const h8*)(zlds + 8); h8 w1 = *(const h8*)(lW + CS);
    dot8_4(v1, w1, c0, c1, c2, c3); }
#pragma unroll
  for (int i = 0; i < 8; i++) Bb[i] = *(const h8*)(gW + (size_t)(8 + i) * CS);
#pragma unroll
  for (int i = 0; i < 8; i++) { h8 v = *(const h8*)(zlds + (2 + i) * 8); dot8_4(v, A[i], c0, c1, c2, c3); }
#pragma unroll
  for (int i = 0; i < 8; i++) A[i] = *(const h8*)(gW + (size_t)(16 + i) * CS);
#pragma unroll
  for (int i = 0; i < 8; i++) { h8 v = *(const h8*)(zlds + (10 + i) * 8); dot8_4(v, Bb[i], c0, c1, c2, c3); }
#pragma unroll
  for (int i = 0; i < 6; i++) Bb[i] = *(const h8*)(gW + (size_t)(24 + i) * CS);
#pragma unroll
  for (int i = 0; i < 8; i++) { h8 v = *(const h8*)(zlds + (18 + i) * 8); dot8_4(v, A[i], c0, c1, c2, c3); }
#pragma unroll
  for (int i = 0; i < 6; i++) { h8 v = *(const h8*)(zlds + (26 + i) * 8); dot8_4(v, Bb[i], c0, c1, c2, c3); }
  return c0 + c1 + c2 + c3;
}

// One 512-thread WG per batch element; no cross-WG communication.
extern "C" __global__ __launch_bounds__(NT, 1)
void cfc2(const float* __restrict__ x, const float* __restrict__ ts,
          const float* __restrict__ bb, const float* __restrict__ bf1,
          const float* __restrict__ bf2, const float* __restrict__ bta,
          const float* __restrict__ btb, const float* __restrict__ bo,
          const _Float16* __restrict__ ws, float* __restrict__ out) {
  extern __shared__ char smem[];
  _Float16* sWo = (_Float16*)(smem + OWO);
  _Float16* sWb = (_Float16*)(smem + OWB);
  _Float16* sW4 = (_Float16*)(smem + OW4);
  _Float16* xh  = (_Float16*)(smem + OXH);   // [0,128): x_t  [128,384): h
  _Float16* zf  = (_Float16*)(smem + OZF);
  float*    tsb = (float*)(smem + OTS);
  float*    scrH = (float*)(smem + OSH);
  float*    scrY = (float*)(smem + OSY);

  const int tid = threadIdx.x;
  const int b = blockIdx.x;
  const _Float16* Wb_p = ws + WB_OFF;
  const _Float16* W4_p = ws + W4_OFF;

  // ---- one-time staging ----
  { const uint4* g = (const uint4*)(ws + WO_OFF);
    uint4* l = (uint4*)(smem + OWO);
    for (int i = tid; i < 4096; i += NT) l[i] = g[i]; }
  { uint4* l = (uint4*)(smem + OWB);          // Wb slices k8: 0..4 and 24..28
    for (int i = tid; i < 2560; i += NT) {
      int s = i >> 8, r = i & 255;
      int k8 = (s < 5) ? s : (19 + s);
      l[i] = ((const uint4*)(ws + (size_t)k8 * 2048))[r];
    } }
  { const uint4* g = (const uint4*)(ws + W4_OFF);   // W4 slices k8 = 0,1
    uint4* l = (uint4*)(smem + OW4);
    for (int i = tid; i < 2048; i += NT) l[i] = g[i]; }
  const float* xrow  = x  + (size_t)b * Sn * FIN;
  const float* tsrow = ts + (size_t)b * Sn;
  float*       orow  = out + (size_t)b * Sn * FOUT;
  for (int i = tid; i < Sn; i += NT) tsb[i] = tsrow[i];
  if (tid < 128) ((unsigned*)xh)[64 + tid] = 0;     // h0 = 0
  if (tid < 64) {                                   // x(0)
    float2 xv = *(const float2*)(xrow + 2 * tid);
    h2 p; p[0] = (_Float16)xv.x; p[1] = (_Float16)xv.y;
    *(h2*)&xh[2 * tid] = p;
  }

  // ---- per-role constants ----
  const int jZ = tid >> 1, khZ = tid & 1;
  const float bbj = bb[jZ];
  const int n0 = tid, n1 = tid + 512;
  const int tl = tid & 255;
  const float bA = (tid < 256) ? bf1[tl] : bf2[tl];
  const float bB = (tid < 256) ? bta[tl] : btb[tl];
  const int jY = tid & 127, kq = tid >> 7;
  const float boj = bo[jY];
  const _Float16* gZ = Wb_p + ((size_t)(khZ * 24 + 5) * 256 + jZ) * 8;
  const _Float16* lZ = sWb + ((size_t)(khZ * 5) * 256 + jZ) * 8;
  const _Float16* gH0 = W4_p + ((size_t)2 * 1024 + n0) * 8;
  const _Float16* gH1 = W4_p + ((size_t)2 * 1024 + n1) * 8;
  const int ZCS = 256 * 8;
  __syncthreads();

  for (int st = 0; st < Sn; ++st) {
    // x(t+1) prefetch (wave 7)
    float2 xv; xv.x = 0.f; xv.y = 0.f;
    if (tid >= 448 && st + 1 < Sn)
      xv = *(const float2*)(xrow + (size_t)(st + 1) * FIN + 2 * (tid - 448));

    // ---- Z: z = tanh([x,h] @ Wb + bb), K split even/odd lanes ----
    h8 A[8], Bb[8];
#pragma unroll
    for (int i = 0; i < 8; i++) A[i] = *(const h8*)(gZ + (size_t)i * ZCS);
    float a0 = 0.f, a1 = 0.f, a2 = 0.f, a3 = 0.f;
#pragma unroll
    for (int c = 0; c < 5; c++) {
      h8 v = *(const h8*)&xh[(khZ * 24 + c) * 8];
      h8 w = *(const h8*)(lZ + (size_t)c * ZCS);
      dot8_4(v, w, a0, a1, a2, a3);
    }
#pragma unroll
    for (int i = 0; i < 8; i++) Bb[i] = *(const h8*)(gZ + (size_t)(8 + i) * ZCS);
#pragma unroll
    for (int i = 0; i < 8; i++) { h8 v = *(const h8*)&xh[(khZ * 24 + 5 + i) * 8]; dot8_4(v, A[i], a0, a1, a2, a3); }
#pragma unroll
    for (int i = 0; i < 3; i++) A[i] = *(const h8*)(gZ + (size_t)(16 + i) * ZCS);
#pragma unroll
    for (int i = 0; i < 8; i++) { h8 v = *(const h8*)&xh[(khZ * 24 + 13 + i) * 8]; dot8_4(v, Bb[i], a0, a1, a2, a3); }
#pragma unroll
    for (int i = 0; i < 3; i++) { h8 v = *(const h8*)&xh[(khZ * 24 + 21 + i) * 8]; dot8_4(v, A[i], a0, a1, a2, a3); }
    float zsum = a0 + a1 + a2 + a3;
    zsum += __shfl_xor(zsum, 1);          // combine the two K-halves in-wave
    if (!khZ) zf[jZ] = (_Float16)tanhf(zsum + bbj);
    __syncthreads();                      // A: Z reads of xh done, zf visible

    if (tid >= 448 && st + 1 < Sn) {      // commit x(t+1) (xh[0..128) idle now)
      h2 p; p[0] = (_Float16)xv.x; p[1] = (_Float16)xv.y;
      *(h2*)&xh[2 * (tid - 448)] = p;
    }

    // ---- H: thread t owns columns n0=t (ff1/ff2) and n1=t+512 (ta/tb) ----
    float v0 = hchain(gH0, zf, sW4 + (size_t)n0 * 8) + bA;
    float v1 = hchain(gH1, zf, sW4 + (size_t)n1 * 8) + bB;
    if (tid >= 256) { float2 o; o.x = v0; o.y = v1; *(float2*)&scrH[(tid - 256) * 2] = o; }
    __syncthreads();                      // B
    if (tid < 256) {
      float2 o = *(const float2*)&scrH[tid * 2];   // (ff2, tb) partner values
      float tt = tsb[st];
      float sg = 1.f / (1.f + __expf(-(v1 * tt + o.y)));
      float hn = tanhf(v0) * (1.f - sg) + sg * tanhf(o.x);
      xh[128 + tid] = (_Float16)hn;
    }
    __syncthreads();                      // C: h visible

    // ---- Y: y = h @ Wout + bo, Wout LDS-resident, K split across wave-pairs ----
    float y0 = 0.f, y1 = 0.f, y2 = 0.f, y3 = 0.f;
#pragma unroll
    for (int i = 0; i < 8; i++) {
      int k8 = kq * 8 + i;
      h8 v = *(const h8*)&xh[128 + k8 * 8];
      h8 w = *(const h8*)&sWo[((size_t)k8 * 128 + jY) * 8];
      dot8_4(v, w, y0, y1, y2, y3);
    }
    float ysm = y0 + y1 + y2 + y3;
    if (kq) scrY[(kq - 1) * 128 + jY] = ysm;
    __syncthreads();                      // D
    if (!kq)
      orow[(size_t)st * FOUT + jY] =
          ysm + scrY[jY] + scrY[128 + jY] + scrY[256 + jY] + boj;
  }
}

extern "C" void kernel_launch(void* const* d_in, const int* in_sizes, int n_in,
                              void* d_out, int out_size, void* d_ws, size_t ws_size,
                              hipStream_t stream) {
  const float* x   = (const float*)d_in[0];
  const float* ts  = (const float*)d_in[1];
  const float* Wb  = (const float*)d_in[2];
  const float* bb  = (const float*)d_in[3];
  const float* W1  = (const float*)d_in[4];
  const float* bf1 = (const float*)d_in[5];
  const float* W2  = (const float*)d_in[6];
  const float* bf2 = (const float*)d_in[7];
  const float* W3  = (const float*)d_in[8];
  const float* bta = (const float*)d_in[9];
  const float* W4  = (const float*)d_in[10];
  const float* btb = (const float*)d_in[11];
  const float* Wo  = (const float*)d_in[12];
  const float* bo  = (const float*)d_in[13];
  float* out = (float*)d_out;
  _Float16* ws = (_Float16*)d_ws;

  pack_w<<<WS_HALVES / 256, 256, 0, stream>>>(Wb, W1, W2, W3, W4, Wo, ws);

  hipFuncSetAttribute((const void*)cfc2,
                      hipFuncAttributeMaxDynamicSharedMemorySize, SMEM2);
  cfc2<<<Bn, NT, SMEM2, stream>>>(x, ts, bb, bf1, bf2, bta, btb, bo, ws, out);
}

// Round 4
// 6606.818 us; speedup vs baseline: 5.3273x; 2.7385x over previous
//
#include <hip/hip_runtime.h>

// B=128, S=1024, F_IN=128, H=256, BB=256, F_OUT=128
#define Bn   128
#define Sn   1024
#define FIN  128
#define Hn   256
#define FOUT 128
#define KBB  384
#define NT1  1024   // phase-1 threads (16 waves)

// packed weight layout in d_ws (halves):
//   Wb_p [48][256][8]  -> 98304
//   W4_p [32][1024][8] -> 262144   (N = [ff1|ff2|ta|tb])
//   Wo_p [32][128][8]  -> 32768
//   hbuf [B*S*H] fp16  -> 33554432 (only if ws_size permits)
#define WB_OFF 0
#define W4_OFF 98304
#define WO_OFF 360448
#define WS_HALVES 393216
#define HBUF_OFF WS_HALVES
#define WS_SPLIT_BYTES ((size_t)(WS_HALVES + (size_t)Bn * Sn * Hn) * 2)

typedef _Float16 h2 __attribute__((ext_vector_type(2)));
typedef _Float16 h8 __attribute__((ext_vector_type(8)));

__device__ __forceinline__ float dot2f(h2 a, h2 b, float c) {
#if __has_builtin(__builtin_amdgcn_fdot2)
  return __builtin_amdgcn_fdot2(a, b, c, false);   // v_dot2_f32_f16
#else
  return c + (float)a[0] * (float)b[0] + (float)a[1] * (float)b[1];
#endif
}
__device__ __forceinline__ void dot8_4(h8 v, h8 w, float& c0, float& c1, float& c2, float& c3) {
  h2 v0 = {v[0], v[1]}, v1 = {v[2], v[3]}, v2 = {v[4], v[5]}, v3 = {v[6], v[7]};
  h2 w0 = {w[0], w[1]}, w1 = {w[2], w[3]}, w2 = {w[4], w[5]}, w3 = {w[6], w[7]};
  c0 = dot2f(v0, w0, c0); c1 = dot2f(v1, w1, c1);
  c2 = dot2f(v2, w2, c2); c3 = dot2f(v3, w3, c3);
}

// fp32 -> fp16 packing (verified layout from round 1)
__global__ __launch_bounds__(256) void pack_w(
    const float* __restrict__ Wb, const float* __restrict__ W1,
    const float* __restrict__ W2, const float* __restrict__ W3,
    const float* __restrict__ W4, const float* __restrict__ Wo,
    _Float16* __restrict__ ws) {
  int p = blockIdx.x * 256 + threadIdx.x;
  if (p >= WS_HALVES) return;
  float v;
  if (p < W4_OFF) {                       // backbone [384,256] row-major
    int r = p & 7, j = (p >> 3) & 255;
    int k = ((p >> 11) << 3) | r;
    v = Wb[k * 256 + j];
  } else if (p < WO_OFF) {                // heads concat: N = [ff1|ff2|ta|tb]
    int q = p - W4_OFF;
    int r = q & 7, j = (q >> 3) & 1023;
    int k = ((q >> 13) << 3) | r;
    int jj = j & 255;
    const float* Ws = (j < 256) ? W1 : (j < 512) ? W2 : (j < 768) ? W3 : W4;
    v = Ws[k * 256 + jj];
  } else {                                // Wout [256,128]
    int q = p - WO_OFF;
    int r = q & 7, j = (q >> 3) & 127;
    int k = ((q >> 10) << 3) | r;
    v = Wo[k * 128 + j];
  }
  ws[p] = (_Float16)v;
}

// Phase 1: one 1024-thread WG per batch element (16 waves = 4/SIMD for latency
// hiding). Weights stream from L2 exactly as in round 1 (sequential chunks,
// 1 KB contiguous per wave-load, unroll-4). K-split across wave groups with
// LDS reduction. INLINE_Y=1 also does the output projection (fallback).
template <int INLINE_Y>
__global__ __launch_bounds__(NT1, 4) void cfc3(
    const float* __restrict__ x, const float* __restrict__ ts,
    const float* __restrict__ bb, const float* __restrict__ bf1,
    const float* __restrict__ bf2, const float* __restrict__ bta,
    const float* __restrict__ btb, const float* __restrict__ bo,
    _Float16* __restrict__ ws, float* __restrict__ out) {
  __shared__ __align__(16) _Float16 xh[KBB];   // [0,128): x_t  [128,384): h
  __shared__ __align__(16) _Float16 zf[Hn];
  __shared__ float tsb[Sn];
  __shared__ float scrZ[768];
  __shared__ float scrH[768];
  __shared__ float scrY[896];

  const int tid = threadIdx.x;
  const int b = blockIdx.x;
  const _Float16* Wb_p = ws + WB_OFF;
  const _Float16* W4_p = ws + W4_OFF;
  const _Float16* Wo_p = ws + WO_OFF;
  _Float16* hbuf = ws + HBUF_OFF;

  const float* xrow  = x  + (size_t)b * Sn * FIN;
  const float* tsrow = ts + (size_t)b * Sn;
  float*       orow  = out + (size_t)b * Sn * FOUT;

  // ---- one-time staging ----
  tsb[tid] = tsrow[tid];                       // NT1 == Sn
  if (tid < 128) ((unsigned*)xh)[64 + tid] = 0;   // h0 = 0 (halves [128,384))
  if (tid < 64) {                              // x(0)
    float2 xv = *(const float2*)(xrow + 2 * tid);
    h2 p; p[0] = (_Float16)xv.x; p[1] = (_Float16)xv.y;
    *(h2*)&xh[2 * tid] = p;
  }

  // ---- per-role constants ----
  const int jq = tid & 255;          // column within a 256 group
  const int kw = tid >> 8;           // Z K-split group (0..3), wave-uniform
  const float bbj = (tid < 256) ? bb[tid] : 0.f;
  const float bH = (kw == 0 ? bf1 : kw == 1 ? bf2 : kw == 2 ? bta : btb)[jq];
  const int jY = tid & 127, kq = tid >> 7;
  const float boj = (tid < 128) ? bo[tid] : 0.f;

  const _Float16* gZ = Wb_p + ((size_t)(kw * 12) * 256 + jq) * 8;  // 12 chunks
  const _Float16* gH = W4_p + (size_t)tid * 8;                     // 32 chunks
  const _Float16* gY = Wo_p + ((size_t)(kq * 4) * 128 + jY) * 8;   // 4 chunks
  __syncthreads();

  for (int st = 0; st < Sn; ++st) {
    // x(t+1) prefetch (wave 15)
    float2 xv; xv.x = 0.f; xv.y = 0.f;
    if (tid >= 960 && st + 1 < Sn)
      xv = *(const float2*)(xrow + (size_t)(st + 1) * FIN + 2 * (tid - 960));

    // ---- Z: z = tanh([x,h] @ Wb + bb); K=384 split into 4 wave-groups ----
    float a0 = 0.f, a1 = 0.f, a2 = 0.f, a3 = 0.f;
#pragma unroll 4
    for (int c = 0; c < 12; ++c) {
      h8 v = *(const h8*)&xh[(kw * 12 + c) * 8];        // LDS broadcast
      h8 w = *(const h8*)(gZ + (size_t)c * 2048);       // 1 KB/wave contiguous
      dot8_4(v, w, a0, a1, a2, a3);
    }
    float zs = a0 + a1 + a2 + a3;
    if (tid >= 256) scrZ[tid - 256] = zs;
    __syncthreads();                     // B1: Z xh-reads done, scrZ ready
    if (tid < 256) {
      float zp = zs + scrZ[tid] + scrZ[256 + tid] + scrZ[512 + tid] + bbj;
      zf[tid] = (_Float16)tanhf(zp);
    }
    if (tid >= 960 && st + 1 < Sn) {     // commit x(t+1); safe after B1
      h2 p; p[0] = (_Float16)xv.x; p[1] = (_Float16)xv.y;
      *(h2*)&xh[2 * (tid - 960)] = p;
    }
    __syncthreads();                     // B2: zf ready

    // ---- H: col n = tid of [ff1|ff2|ta|tb], K=256 ----
    float b0 = 0.f, b1 = 0.f, b2 = 0.f, b3 = 0.f;
#pragma unroll 4
    for (int c = 0; c < 32; ++c) {
      h8 v = *(const h8*)&zf[c * 8];                    // LDS broadcast
      h8 w = *(const h8*)(gH + (size_t)c * 8192);       // 1 KB/wave contiguous
      dot8_4(v, w, b0, b1, b2, b3);
    }
    float g = b0 + b1 + b2 + b3 + bH;
    if (tid >= 256) scrH[tid - 256] = g;
    __syncthreads();                     // B3: scrH ready
    if (tid < 256) {
      float ff2 = scrH[tid], ta = scrH[256 + tid], tb = scrH[512 + tid];
      float tt = tsb[st];
      float sg = 1.f / (1.f + __expf(-(ta * tt + tb)));
      float hn = tanhf(g) * (1.f - sg) + sg * tanhf(ff2);
      xh[128 + tid] = (_Float16)hn;
      if (!INLINE_Y)
        hbuf[((size_t)b * Sn + st) * Hn + tid] = (_Float16)hn;
    }
    __syncthreads();                     // B4: h ready

    if (INLINE_Y) {
      // ---- Y: y = h @ Wout + bo, K split 8 ways ----
      float y0 = 0.f, y1 = 0.f, y2 = 0.f, y3 = 0.f;
#pragma unroll
      for (int c = 0; c < 4; ++c) {
        h8 v = *(const h8*)&xh[128 + (kq * 4 + c) * 8];
        h8 w = *(const h8*)(gY + (size_t)c * 1024);
        dot8_4(v, w, y0, y1, y2, y3);
      }
      float ys = y0 + y1 + y2 + y3;
      if (tid >= 128) scrY[tid - 128] = ys;
      __syncthreads();                   // B5
      if (tid < 128) {
        float y = ys + boj;
#pragma unroll
        for (int p = 0; p < 7; ++p) y += scrY[128 * p + tid];
        orow[(size_t)st * FOUT + tid] = y;
      }
    }
  }
}

// Phase 2 (split path): y[BS,128] = h[BS,256] @ Wout + bo. Wout LDS-resident,
// h rows staged 8 at a time; 512 WGs x 256 threads over all 256 CUs.
#define SMEMY (65536 + 4096)
extern "C" __global__ __launch_bounds__(256, 4)
void ygemm(const _Float16* __restrict__ ws, const float* __restrict__ bo,
           float* __restrict__ out) {
  extern __shared__ char ysm[];
  _Float16* sWo = (_Float16*)ysm;            // 32768 halves
  _Float16* sH  = (_Float16*)(ysm + 65536);  // 8 x 256 halves
  const int tid = threadIdx.x;
  { const uint4* g = (const uint4*)(ws + WO_OFF);
    uint4* l = (uint4*)sWo;
#pragma unroll
    for (int i = 0; i < 16; ++i) l[tid + 256 * i] = g[tid + 256 * i]; }
  const _Float16* hb = ws + HBUF_OFF;
  const int row0 = blockIdx.x * 256;
  const int j = tid & 127, rh = tid >> 7;
  const float boj = bo[j];
  for (int it = 0; it < 32; ++it) {
    const int rbase = row0 + it * 8;
    __syncthreads();                         // sH reads from prev iter done
    ((uint4*)sH)[tid] = ((const uint4*)(hb + (size_t)rbase * 256))[tid];
    __syncthreads();
#pragma unroll
    for (int rr = rh; rr < 8; rr += 2) {
      float y0 = 0.f, y1 = 0.f, y2 = 0.f, y3 = 0.f;
#pragma unroll 4
      for (int c = 0; c < 32; ++c) {
        h8 v = *(const h8*)&sH[rr * 256 + c * 8];       // broadcast
        h8 w = *(const h8*)&sWo[((size_t)c * 128 + j) * 8];
        dot8_4(v, w, y0, y1, y2, y3);
      }
      out[(size_t)(rbase + rr) * 128 + j] = y0 + y1 + y2 + y3 + boj;
    }
  }
}

extern "C" void kernel_launch(void* const* d_in, const int* in_sizes, int n_in,
                              void* d_out, int out_size, void* d_ws, size_t ws_size,
                              hipStream_t stream) {
  const float* x   = (const float*)d_in[0];
  const float* ts  = (const float*)d_in[1];
  const float* Wb  = (const float*)d_in[2];
  const float* bb  = (const float*)d_in[3];
  const float* W1  = (const float*)d_in[4];
  const float* bf1 = (const float*)d_in[5];
  const float* W2  = (const float*)d_in[6];
  const float* bf2 = (const float*)d_in[7];
  const float* W3  = (const float*)d_in[8];
  const float* bta = (const float*)d_in[9];
  const float* W4  = (const float*)d_in[10];
  const float* btb = (const float*)d_in[11];
  const float* Wo  = (const float*)d_in[12];
  const float* bo  = (const float*)d_in[13];
  float* out = (float*)d_out;
  _Float16* ws = (_Float16*)d_ws;

  pack_w<<<WS_HALVES / 256, 256, 0, stream>>>(Wb, W1, W2, W3, W4, Wo, ws);

  if (ws_size >= WS_SPLIT_BYTES) {
    cfc3<0><<<Bn, NT1, 0, stream>>>(x, ts, bb, bf1, bf2, bta, btb, bo, ws, out);
    hipFuncSetAttribute((const void*)ygemm,
                        hipFuncAttributeMaxDynamicSharedMemorySize, SMEMY);
    ygemm<<<(Bn * Sn) / 256, 256, SMEMY, stream>>>(ws, bo, out);
  } else {
    cfc3<1><<<Bn, NT1, 0, stream>>>(x, ts, bb, bf1, bf2, bta, btb, bo, ws, out);
  }
}